// Round 7
// baseline (250.443 us; speedup 1.0000x reference)
//
#include <hip/hip_runtime.h>
#include <hip/hip_bf16.h>

typedef unsigned int u32;
typedef unsigned short u16;
typedef unsigned long long u64;
typedef __attribute__((ext_vector_type(8))) short short8;
typedef __attribute__((ext_vector_type(4))) float f32x4;

#define BATCH 4
#define SEQ   4096
#define DIM   768
#define HD    64
#define NROW  (BATCH*SEQ)   // 16384
#define LOG2E 1.44269504088896f
#define SSCALE (0.125f * LOG2E)
#define CSHIFT (-32.0f)      // fixed exp2-domain shift (softmax shift-invariant)
#define NEGBIG (-1.0e30f)
#define VSTRIDE 4224         // vT row stride in u16 (breaks L2 channel camping)
#define PSLOTB 2176          // partial slot: 2048 B bf16 O[16][64] + 64 B f32 l[16] + pad

__device__ __forceinline__ float ex2(float x) { return __builtin_amdgcn_exp2f(x); }
__device__ __forceinline__ float bfbits2f(u16 u) {
    return __uint_as_float(((u32)u) << 16);
}
__device__ __forceinline__ u16 f2bf(float f) {
    return (u16)((__float_as_uint(f) + 0x8000u) >> 16);
}
__device__ __forceinline__ u32 pkbf(float a, float b) { // lo16=bf(a), hi16=bf(b)
    u32 xa = __float_as_uint(a) + 0x8000u;
    u32 xb = __float_as_uint(b) + 0x8000u;
    return __builtin_amdgcn_perm(xb, xa, 0x07060302);
}
// Deterministic per-wave dtype sniff (same answer in every wave/block).
__device__ __forceinline__ int sniff_bf16(const u32* x) {
    u32 w = x[threadIdx.x & 63];
    u32 lo = w & 0xffffu;
    u32 e  = (lo >> 7) & 0xffu;
    bool ok = (lo == 0u) || (e >= 96u && e <= 134u);
    u64 bal = __ballot(ok);
    return (__popcll(bal) >= 48) ? 1 : 0;
}

// ---------------- QKV projection: barrier-free register GEMM ----------------
// Blocks 0..255: 64 rows x 192 cols, 8 waves = 4 strips x 2 col-halves.
// A (X rows) and B (W rows) fragments loaded DIRECTLY from global with
// register prefetch (A ping-pong one kc ahead; W reloaded post-consumption).
// Blocks 256..257: bit-pack padding mask via ballot.
__global__ __launch_bounds__(512, 2) void qkv_kernel(
    const void* __restrict__ x,
    const void* __restrict__ wq, const void* __restrict__ wk,
    const void* __restrict__ wv, const int* __restrict__ mask,
    u16* __restrict__ qws, u16* __restrict__ kws, u16* __restrict__ vTws,
    u32* __restrict__ mb)
{
    const int t = threadIdx.x;
    const int l = t & 63;
    const int w = t >> 6;

    if (blockIdx.x >= 256) {            // ---- mask bit-pack ----
        const int base = (blockIdx.x - 256) * 8192 + w * 1024;
#pragma unroll
        for (int it = 0; it < 16; ++it) {
            const int idx = base + it * 64 + l;
            u64 bal = __ballot(mask[idx] != 0);
            if (l == 0)       mb[idx >> 5] = (u32)bal;
            else if (l == 32) mb[idx >> 5] = (u32)(bal >> 32);
        }
        return;
    }

    const int flag = sniff_bf16((const u32*)x);
    __shared__ u16 Vt[64][66];
    const int li = l & 15;
    const int g  = l >> 4;
    const int strip = w & 3;            // 16-row strip
    const int nhalf = w >> 2;           // 96-col half
    const int m0 = blockIdx.x * 64;
    const int b  = m0 >> 12;

    f32x4 acc[6];
#pragma unroll
    for (int i = 0; i < 6; ++i) acc[i] = (f32x4){0.f, 0.f, 0.f, 0.f};

    const long xoff = (long)(m0 + strip * 16 + li) * DIM + g * 8;
    const void* wsrc[6]; long woff[6];
#pragma unroll
    for (int ns = 0; ns < 6; ++ns) {
        const int n0 = nhalf * 96 + ns * 16;
        wsrc[ns] = (n0 < 64) ? wq : (n0 < 128) ? wk : wv;
        woff[ns] = (long)((n0 & 63) + li) * DIM + g * 8;
    }

    auto ldbf = [&](const void* bp, long off) -> short8 {
        if (flag) return *reinterpret_cast<const short8*>((const u16*)bp + off);
        const float* p = (const float*)bp + off;
        float4 a = *reinterpret_cast<const float4*>(p);
        float4 c = *reinterpret_cast<const float4*>(p + 4);
        union { u32 u[4]; short8 s; } un;
        un.u[0] = pkbf(a.x, a.y); un.u[1] = pkbf(a.z, a.w);
        un.u[2] = pkbf(c.x, c.y); un.u[3] = pkbf(c.z, c.w);
        return un.s;
    };

    short8 wa[12];
#pragma unroll
    for (int ns = 0; ns < 6; ++ns) {
        wa[2*ns]   = ldbf(wsrc[ns], woff[ns]);
        wa[2*ns+1] = ldbf(wsrc[ns], woff[ns] + 32);
    }
    short8 afa0 = ldbf(x, xoff);
    short8 afa1 = ldbf(x, xoff + 32);
    short8 afb0, afb1;

#pragma unroll
    for (int kc = 0; kc < 12; kc += 2) {
        // prefetch A for kc+1 before consuming kc
        {
            const long o = (long)(kc + 1) * 64;
            afb0 = ldbf(x, xoff + o);
            afb1 = ldbf(x, xoff + o + 32);
        }
#pragma unroll
        for (int ns = 0; ns < 6; ++ns) {
            acc[ns] = __builtin_amdgcn_mfma_f32_16x16x32_bf16(afa0, wa[2*ns],   acc[ns], 0, 0, 0);
            acc[ns] = __builtin_amdgcn_mfma_f32_16x16x32_bf16(afa1, wa[2*ns+1], acc[ns], 0, 0, 0);
            const long o = (long)(kc + 1) * 64;
            wa[2*ns]   = ldbf(wsrc[ns], woff[ns] + o);
            wa[2*ns+1] = ldbf(wsrc[ns], woff[ns] + o + 32);
        }
        if (kc + 2 < 12) {
            const long o = (long)(kc + 2) * 64;
            afa0 = ldbf(x, xoff + o);
            afa1 = ldbf(x, xoff + o + 32);
        }
#pragma unroll
        for (int ns = 0; ns < 6; ++ns) {
            acc[ns] = __builtin_amdgcn_mfma_f32_16x16x32_bf16(afb0, wa[2*ns],   acc[ns], 0, 0, 0);
            acc[ns] = __builtin_amdgcn_mfma_f32_16x16x32_bf16(afb1, wa[2*ns+1], acc[ns], 0, 0, 0);
            if (kc + 2 < 12) {
                const long o = (long)(kc + 2) * 64;
                wa[2*ns]   = ldbf(wsrc[ns], woff[ns] + o);
                wa[2*ns+1] = ldbf(wsrc[ns], woff[ns] + o + 32);
            }
        }
    }

    // epilogue: C row = m0 + strip*16 + 4g + r, col n = nhalf*96 + ns*16 + li
#pragma unroll
    for (int ns = 0; ns < 6; ++ns) {
        const int n = nhalf * 96 + ns * 16 + li;
#pragma unroll
        for (int r = 0; r < 4; ++r) {
            const int rowl = strip * 16 + 4 * g + r;
            u16 bv = f2bf(acc[ns][r]);
            if (n < 64)        qws[(long)(m0 + rowl) * HD + n]        = bv;
            else if (n < 128)  kws[(long)(m0 + rowl) * HD + (n - 64)] = bv;
            else               Vt[rowl][n - 128]                      = bv;
        }
    }
    __syncthreads();
    // transpose v out: vT[(b*64+d)][ (m0&4095) + mg*8 .. +7 ], padded stride
    {
        const int d  = t >> 3;   // 0..63
        const int mg = t & 7;    // 0..7
        union { u16 h[8]; short8 s; } u;
#pragma unroll
        for (int i = 0; i < 8; ++i) u.h[i] = Vt[mg * 8 + i][d];
        u16* dst = vTws + ((long)(b * 64 + d)) * VSTRIDE + (m0 & (SEQ - 1)) + mg * 8;
        *reinterpret_cast<short8*>(dst) = u.s;
    }
}

// ---------------- Flash attention: software-pipelined K-loop ----------------
// Iteration i runs PV(i) interleaved with S-phase(i+1): A-frags come from a
// double-buffered Ps written one iteration earlier (LDS latency hidden), K is
// register-prefetched 2 tiles ahead, V issued at iteration top. Fixed-shift
// exp2 softmax (no running max). Ps overlays the Ow combine buffer
// (barrier-separated) to keep LDS at 18.7 KB.
__global__ __launch_bounds__(256, 3) void attn_kernel(
    const u32* __restrict__ xs,
    const u16* __restrict__ qw, const u16* __restrict__ kw,
    const u16* __restrict__ vTw, const u32* __restrict__ maskbits,
    char* __restrict__ part, void* __restrict__ out)
{
    __shared__ __align__(16) char smraw[18432];   // Ps[4][2][16][72] u16 / Ow[4][16][64] f32
    __shared__ float lwS[4][16];
    u16   (*Ps)[2][16][72] = reinterpret_cast<u16(*)[2][16][72]>(smraw);
    float (*Ow)[16][64]    = reinterpret_cast<float(*)[16][64]>(smraw);

    const int flag = sniff_bf16(xs);
    const int t  = threadIdx.x;
    const int l  = t & 63;
    const int w  = t >> 6;
    const int li = l & 15;
    const int g  = l >> 4;
    const int g4 = g * 4;

    const int bid = blockIdx.x;
    const int b   = bid & 3;
    const int u   = bid >> 2;
    int qt16, c;
    if (u < 256) { qt16 = 255 - (u >> 1); c = u & 1; }
    else         { qt16 = 383 - u;        c = 0;     }
    const int q0    = qt16 * 16;
    const int nkt   = (qt16 >> 2) + 1;
    const int ktBeg = c * 32;
    const int ktEnd = min(ktBeg + 32, nkt);
    const int nc    = (qt16 >= 128) ? 2 : 1;

    // Q fragments (B-operand): lane holds Q[q0+li][g*8+j (+32)]
    const u16* qrow = qw + ((long)(b * SEQ + q0 + li)) * HD + g * 8;
    short8 qf0 = *reinterpret_cast<const short8*>(qrow);
    short8 qf1 = *reinterpret_cast<const short8*>(qrow + 32);

    short8 ones;
#pragma unroll
    for (int i = 0; i < 8; ++i) ones[i] = (short)0x3F80;  // bf16 1.0

    f32x4 O[4];
#pragma unroll
    for (int i = 0; i < 4; ++i) O[i] = (f32x4){0.f, 0.f, 0.f, 0.f};
    f32x4 l4 = (f32x4){0.f, 0.f, 0.f, 0.f};
    const int qg = q0 + li;
    const f32x4 z4 = (f32x4){0.f, 0.f, 0.f, 0.f};

    const u16* kbase = kw  + ((long)(b * SEQ) + li) * HD + g * 8;
    const u16* vbase = vTw + ((long)(b * 64)  + li) * VSTRIDE + g * 8;

    const int kt0 = ktBeg + w;
    const int ntile = (kt0 < ktEnd) ? (((ktEnd - kt0) + 3) >> 2) : 0;
    const int toffLast = (ntile - 1) * 4;

    short8 ka[8];
    auto kload = [&](int toff) {                  // clamped prefetch
        const int tt = (toff > toffLast) ? toffLast : toff;
        const u16* kp = kbase + (long)((kt0 + tt) * 64) * HD;
#pragma unroll
        for (int sub = 0; sub < 4; ++sub) {
            ka[2*sub]   = *reinterpret_cast<const short8*>(kp + sub * 16 * HD);
            ka[2*sub+1] = *reinterpret_cast<const short8*>(kp + sub * 16 * HD + 32);
        }
    };
    auto sphase = [&](int toff, int pb) {         // S^T + softmax -> Ps[w][pb]
        const int k0 = (kt0 + toff) * 64;
        const u32 mb0 = maskbits[b * 128 + (k0 >> 5)];
        const u32 mb1 = maskbits[b * 128 + (k0 >> 5) + 1];
#pragma unroll
        for (int sub = 0; sub < 4; ++sub) {
            f32x4 a = __builtin_amdgcn_mfma_f32_16x16x32_bf16(ka[2*sub],   qf0, z4, 0, 0, 0);
            a       = __builtin_amdgcn_mfma_f32_16x16x32_bf16(ka[2*sub+1], qf1, a,  0, 0, 0);
            const u32 word = (sub & 2) ? mb1 : mb0;
            float p[4];
#pragma unroll
            for (int r = 0; r < 4; ++r) {
                const int kloc = sub * 16 + g4 + r;
                const bool keep = ((k0 + kloc) <= qg) &&
                                  (((word >> ((sub & 1) * 16 + g4 + r)) & 1u) != 0u);
                p[r] = ex2(fmaf(a[r], SSCALE, keep ? CSHIFT : NEGBIG));
            }
            uint2 pk = make_uint2(pkbf(p[0], p[1]), pkbf(p[2], p[3]));
            *reinterpret_cast<uint2*>(&Ps[w][pb][li][sub * 16 + g4]) = pk;
        }
    };

    if (ntile > 0) {
        kload(0);
        sphase(0, 0);
        kload(4);
    }
    for (int i = 0; i < ntile; ++i) {
        const int k0 = (kt0 + 4 * i) * 64;
        short8 vf[8];
#pragma unroll
        for (int ds = 0; ds < 4; ++ds) {
            const u16* vr = vbase + (long)(ds * 16) * VSTRIDE + k0;
            vf[2*ds]   = *reinterpret_cast<const short8*>(vr);
            vf[2*ds+1] = *reinterpret_cast<const short8*>(vr + 32);
        }
        const int bufA = i & 1;
        short8 A1 = *reinterpret_cast<const short8*>(&Ps[w][bufA][li][g * 8]);
        short8 A2 = *reinterpret_cast<const short8*>(&Ps[w][bufA][li][32 + g * 8]);
        if (i + 1 < ntile) {
            sphase(4 * (i + 1), bufA ^ 1);        // overlaps PV(i) below
            kload(4 * (i + 2));
        }
        f32x4 lt = __builtin_amdgcn_mfma_f32_16x16x32_bf16(A1, ones, z4, 0, 0, 0);
        lt       = __builtin_amdgcn_mfma_f32_16x16x32_bf16(A2, ones, lt, 0, 0, 0);
#pragma unroll
        for (int r = 0; r < 4; ++r) l4[r] += lt[r];
#pragma unroll
        for (int ds = 0; ds < 4; ++ds) {
            O[ds] = __builtin_amdgcn_mfma_f32_16x16x32_bf16(A1, vf[2*ds],   O[ds], 0, 0, 0);
            O[ds] = __builtin_amdgcn_mfma_f32_16x16x32_bf16(A2, vf[2*ds+1], O[ds], 0, 0, 0);
        }
    }

    __syncthreads();   // all Ps reads done before Ow overlay writes
#pragma unroll
    for (int ds = 0; ds < 4; ++ds)
#pragma unroll
        for (int r = 0; r < 4; ++r)
            Ow[w][g4 + r][ds * 16 + li] = O[ds][r];
    if (li == 0) {
#pragma unroll
        for (int r = 0; r < 4; ++r) lwS[w][g4 + r] = l4[r];
    }
    __syncthreads();

    // combine 4 wave partials (plain sums); thread -> (q = t>>4, d4 = (t&15)*4)
    {
        const int qq = t >> 4;
        const int dd = (t & 15) * 4;
        float L = lwS[0][qq] + lwS[1][qq] + lwS[2][qq] + lwS[3][qq];
        float4 o0 = *reinterpret_cast<const float4*>(&Ow[0][qq][dd]);
        float4 o1 = *reinterpret_cast<const float4*>(&Ow[1][qq][dd]);
        float4 o2 = *reinterpret_cast<const float4*>(&Ow[2][qq][dd]);
        float4 o3 = *reinterpret_cast<const float4*>(&Ow[3][qq][dd]);
        float rx = o0.x + o1.x + o2.x + o3.x;
        float ry = o0.y + o1.y + o2.y + o3.y;
        float rz = o0.z + o1.z + o2.z + o3.z;
        float rw = o0.w + o1.w + o2.w + o3.w;
        if (nc == 1) {
            const float rl = (L > 0.f) ? 1.f / L : 0.f;
            rx *= rl; ry *= rl; rz *= rl; rw *= rl;
            const long row = (long)(b * SEQ + q0 + qq);
            if (flag) {
                uint2 st = make_uint2(pkbf(rx, ry), pkbf(rz, rw));
                *reinterpret_cast<uint2*>((u16*)out + row * HD + dd) = st;
            } else {
                *reinterpret_cast<float4*>((float*)out + row * HD + dd) =
                    make_float4(rx, ry, rz, rw);
            }
        } else {
            char* slot = part + ((long)((b * 128 + (qt16 - 128)) * 2 + c)) * PSLOTB;
            uint2 st = make_uint2(pkbf(rx, ry), pkbf(rz, rw));
            *reinterpret_cast<uint2*>((u16*)slot + qq * 64 + dd) = st;
            if ((t & 15) == 0)
                *reinterpret_cast<float*>(slot + 2048 + qq * 4) = L;
        }
    }
}

// ---------------- merge split-K partials (qt16 >= 128): plain sum ----------
__global__ __launch_bounds__(256) void merge_kernel(
    const u32* __restrict__ xs, const char* __restrict__ part,
    void* __restrict__ out)
{
    const int flag = sniff_bf16(xs);
    const int bid = blockIdx.x;         // 512
    const int b    = bid & 3;
    const int qt16 = 128 + (bid >> 2);
    const int t  = threadIdx.x;
    const int qq = t >> 4;
    const int dd = (t & 15) * 4;
    const char* s0 = part + ((long)((b * 128 + (qt16 - 128)) * 2)) * PSLOTB;
    const char* s1 = s0 + PSLOTB;
    float l0 = *reinterpret_cast<const float*>(s0 + 2048 + qq * 4);
    float l1 = *reinterpret_cast<const float*>(s1 + 2048 + qq * 4);
    float L  = l0 + l1;
    float rl = (L > 0.f) ? 1.f / L : 0.f;
    ushort4 a0 = *reinterpret_cast<const ushort4*>((const u16*)s0 + qq * 64 + dd);
    ushort4 a1 = *reinterpret_cast<const ushort4*>((const u16*)s1 + qq * 64 + dd);
    float rx = (bfbits2f(a0.x) + bfbits2f(a1.x)) * rl;
    float ry = (bfbits2f(a0.y) + bfbits2f(a1.y)) * rl;
    float rz = (bfbits2f(a0.z) + bfbits2f(a1.z)) * rl;
    float rw = (bfbits2f(a0.w) + bfbits2f(a1.w)) * rl;
    const long row = (long)(b * SEQ + qt16 * 16 + qq);
    if (flag) {
        uint2 st = make_uint2(pkbf(rx, ry), pkbf(rz, rw));
        *reinterpret_cast<uint2*>((u16*)out + row * HD + dd) = st;
    } else {
        *reinterpret_cast<float4*>((float*)out + row * HD + dd) =
            make_float4(rx, ry, rz, rw);
    }
}

extern "C" void kernel_launch(void* const* d_in, const int* in_sizes, int n_in,
                              void* d_out, int out_size, void* d_ws, size_t ws_size,
                              hipStream_t stream) {
    const void* x   = d_in[0];
    const int* mask = (const int*)d_in[1];
    const void* wq  = d_in[2];
    const void* wk  = d_in[3];
    const void* wv  = d_in[4];
    const u32* xs   = (const u32*)x;

    u16* q    = (u16*)d_ws;                          // 2 MB
    u16* k    = q  + (long)NROW * HD;                // 2 MB
    u16* vT   = k  + (long)NROW * HD;                // 2.06 MB
    u32* mb   = (u32*)(vT + (long)BATCH * 64 * VSTRIDE);  // 2 KB
    char* part = (char*)(mb + 512);                  // 2.13 MB

    qkv_kernel  <<<258, 512, 0, stream>>>(x, wq, wk, wv, mask, q, k, vT, mb);
    attn_kernel <<<4 * 384, 256, 0, stream>>>(xs, q, k, vT, mb, part, d_out);
    merge_kernel<<<512, 256, 0, stream>>>(xs, part, d_out);
}

// Round 8
// 197.353 us; speedup vs baseline: 1.2690x; 1.2690x over previous
//
#include <hip/hip_runtime.h>
#include <hip/hip_bf16.h>

typedef unsigned int u32;
typedef unsigned short u16;
typedef unsigned long long u64;
typedef __attribute__((ext_vector_type(8))) short short8;
typedef __attribute__((ext_vector_type(4))) float f32x4;

#define BATCH 4
#define SEQ   4096
#define DIM   768
#define HD    64
#define NROW  (BATCH*SEQ)   // 16384
#define LOG2E 1.44269504088896f
#define SSCALE (0.125f * LOG2E)
#define CSHIFT (-32.0f)      // fixed exp2-domain shift (softmax shift-invariant)
#define NEGBIG (-1.0e30f)
#define VSTRIDE 4224         // vT row stride in u16 (breaks L2 channel camping)
#define PSLOTB 2176          // partial slot: 2048 B bf16 O[16][64] + 64 B f32 l[16] + pad

__device__ __forceinline__ float ex2(float x) { return __builtin_amdgcn_exp2f(x); }
__device__ __forceinline__ float bfbits2f(u16 u) {
    return __uint_as_float(((u32)u) << 16);
}
__device__ __forceinline__ u16 f2bf(float f) {
    return (u16)((__float_as_uint(f) + 0x8000u) >> 16);
}
__device__ __forceinline__ u32 pkbf(float a, float b) { // lo16=bf(a), hi16=bf(b)
    u32 xa = __float_as_uint(a) + 0x8000u;
    u32 xb = __float_as_uint(b) + 0x8000u;
    return __builtin_amdgcn_perm(xb, xa, 0x07060302);
}
// Deterministic per-wave dtype sniff (same answer in every wave/block).
__device__ __forceinline__ int sniff_bf16(const u32* x) {
    u32 w = x[threadIdx.x & 63];
    u32 lo = w & 0xffffu;
    u32 e  = (lo >> 7) & 0xffu;
    bool ok = (lo == 0u) || (e >= 96u && e <= 134u);
    u64 bal = __ballot(ok);
    return (__popcll(bal) >= 48) ? 1 : 0;
}

// ---------------- QKV projection: LDS-tiled GEMM (m97 shape) ----------------
// Blocks 0..255: block tile = 64 rows x 192 cols, K staged 64-wide in LDS
// (X 8 KB + W 24 KB, chunk^(row&7) swizzle), register prefetch of next tile.
// 8 waves = 4 row-strips x 2 col-halves: 12 MFMA + 14 ds_read_b128 per K-step.
// Blocks 256..257: bit-pack padding mask via ballot.
__global__ __launch_bounds__(512, 4) void qkv_kernel(
    const void* __restrict__ x,
    const void* __restrict__ wq, const void* __restrict__ wk,
    const void* __restrict__ wv, const int* __restrict__ mask,
    u16* __restrict__ qws, u16* __restrict__ kws, u16* __restrict__ vTws,
    u32* __restrict__ mb)
{
    const int t = threadIdx.x;
    const int l = t & 63;
    const int w = t >> 6;

    if (blockIdx.x >= 256) {            // ---- mask bit-pack ----
        const int base = (blockIdx.x - 256) * 8192 + w * 1024;
#pragma unroll
        for (int it = 0; it < 16; ++it) {
            const int idx = base + it * 64 + l;
            u64 bal = __ballot(mask[idx] != 0);
            if (l == 0)       mb[idx >> 5] = (u32)bal;
            else if (l == 32) mb[idx >> 5] = (u32)(bal >> 32);
        }
        return;
    }

    const int flag = sniff_bf16((const u32*)x);
    __shared__ __align__(16) u16 Xl[64 * 64];    // 8 KB,  slot r*64 + cc*8
    __shared__ __align__(16) u16 Wl[192 * 64];   // 24 KB, slot n*64 + cc*8
    __shared__ u16 Vt[64][66];                   // 8.4 KB transpose staging

    const int li = l & 15;
    const int g  = l >> 4;
    const int g4 = g * 4;
    const int strip = w & 3;            // 16-row strip
    const int nhalf = w >> 2;           // 96-col half
    const int m0 = blockIdx.x * 64;
    const int b  = m0 >> 12;

    auto ldbf = [&](const void* bp, long off) -> short8 {
        if (flag) return *reinterpret_cast<const short8*>((const u16*)bp + off);
        const float* p = (const float*)bp + off;
        float4 a = *reinterpret_cast<const float4*>(p);
        float4 c = *reinterpret_cast<const float4*>(p + 4);
        union { u32 u[4]; short8 s; } un;
        un.u[0] = pkbf(a.x, a.y); un.u[1] = pkbf(a.z, a.w);
        un.u[2] = pkbf(c.x, c.y); un.u[3] = pkbf(c.z, c.w);
        return un.s;
    };

    // ---- staging source mapping (kc-invariant parts) ----
    // X: thread t -> row xr, swizzled chunk xcc holds source chunk xc
    const int xr = t >> 3, xcc = t & 7, xc = xcc ^ (xr & 7);
    const long xsoff = (long)(m0 + xr) * DIM + xc * 8;
    // W: 3 rounds of 512 slots
    const void* wsel[3]; long wsoff[3]; int wdst[3];
#pragma unroll
    for (int j = 0; j < 3; ++j) {
        const int idx = j * 512 + t;
        const int r = idx >> 3, cc = idx & 7, c = cc ^ (r & 7);
        wsel[j] = (r < 64) ? wq : (r < 128) ? wk : wv;
        wsoff[j] = (long)(r & 63) * DIM + c * 8;
        wdst[j]  = idx * 8;             // u16 offset into Wl
    }

    // ---- fragment read offsets (kc-invariant, u16 units) ----
    const int am = strip * 16 + li;
    const int a0off = am * 64 + ((g       ^ (am & 7)) * 8);
    const int a1off = am * 64 + (((g | 4) ^ (am & 7)) * 8);
    int boff[12];
#pragma unroll
    for (int ns = 0; ns < 6; ++ns) {
        const int n = nhalf * 96 + ns * 16 + li;
        boff[2*ns]   = n * 64 + ((g       ^ (n & 7)) * 8);
        boff[2*ns+1] = n * 64 + (((g | 4) ^ (n & 7)) * 8);
    }

    f32x4 acc[6];
#pragma unroll
    for (int i = 0; i < 6; ++i) acc[i] = (f32x4){0.f, 0.f, 0.f, 0.f};

    // preload kc=0 staging registers
    short8 xs  = ldbf(x, xsoff);
    short8 ws0 = ldbf(wsel[0], wsoff[0]);
    short8 ws1 = ldbf(wsel[1], wsoff[1]);
    short8 ws2 = ldbf(wsel[2], wsoff[2]);

    for (int kc = 0; kc < 12; ++kc) {
        __syncthreads();                 // previous K-step's LDS reads done
        *reinterpret_cast<short8*>(&Xl[t * 8])    = xs;
        *reinterpret_cast<short8*>(&Wl[wdst[0]])  = ws0;
        *reinterpret_cast<short8*>(&Wl[wdst[1]])  = ws1;
        *reinterpret_cast<short8*>(&Wl[wdst[2]])  = ws2;
        if (kc < 11) {                   // prefetch next staging tile
            const long o = (long)(kc + 1) * 64;
            xs  = ldbf(x, xsoff + o);
            ws0 = ldbf(wsel[0], wsoff[0] + o);
            ws1 = ldbf(wsel[1], wsoff[1] + o);
            ws2 = ldbf(wsel[2], wsoff[2] + o);
        }
        __syncthreads();                 // staging visible
        short8 af0 = *reinterpret_cast<const short8*>(&Xl[a0off]);
        short8 af1 = *reinterpret_cast<const short8*>(&Xl[a1off]);
#pragma unroll
        for (int ns = 0; ns < 6; ++ns) {
            short8 b0 = *reinterpret_cast<const short8*>(&Wl[boff[2*ns]]);
            short8 b1 = *reinterpret_cast<const short8*>(&Wl[boff[2*ns+1]]);
            acc[ns] = __builtin_amdgcn_mfma_f32_16x16x32_bf16(af0, b0, acc[ns], 0, 0, 0);
            acc[ns] = __builtin_amdgcn_mfma_f32_16x16x32_bf16(af1, b1, acc[ns], 0, 0, 0);
        }
    }

    // epilogue: C row = m0 + strip*16 + g4 + r, col n = nhalf*96 + ns*16 + li
#pragma unroll
    for (int ns = 0; ns < 6; ++ns) {
        const int n = nhalf * 96 + ns * 16 + li;
#pragma unroll
        for (int r = 0; r < 4; ++r) {
            const int rowl = strip * 16 + g4 + r;
            u16 bv = f2bf(acc[ns][r]);
            if (n < 64)        qws[(long)(m0 + rowl) * HD + n]        = bv;
            else if (n < 128)  kws[(long)(m0 + rowl) * HD + (n - 64)] = bv;
            else               Vt[rowl][n - 128]                      = bv;
        }
    }
    __syncthreads();
    // transpose v out: vT[(b*64+d)][ (m0&4095) + mg*8 .. +7 ], padded stride
    {
        const int d  = t >> 3;   // 0..63
        const int mg = t & 7;    // 0..7
        union { u16 h[8]; short8 s; } u;
#pragma unroll
        for (int i = 0; i < 8; ++i) u.h[i] = Vt[mg * 8 + i][d];
        u16* dst = vTws + ((long)(b * 64 + d)) * VSTRIDE + (m0 & (SEQ - 1)) + mg * 8;
        *reinterpret_cast<short8*>(dst) = u.s;
    }
}

// ---------------- Flash attention: software-pipelined K-loop ----------------
// Iteration i runs PV(i) interleaved with S-phase(i+1): A-frags come from a
// double-buffered Ps written one iteration earlier, K register-prefetched 2
// tiles ahead, V issued at iteration top. Fixed-shift exp2 softmax.
__global__ __launch_bounds__(256, 3) void attn_kernel(
    const u32* __restrict__ xs,
    const u16* __restrict__ qw, const u16* __restrict__ kw,
    const u16* __restrict__ vTw, const u32* __restrict__ maskbits,
    char* __restrict__ part, void* __restrict__ out)
{
    __shared__ __align__(16) char smraw[18432];   // Ps[4][2][16][72] u16 / Ow[4][16][64] f32
    __shared__ float lwS[4][16];
    u16   (*Ps)[2][16][72] = reinterpret_cast<u16(*)[2][16][72]>(smraw);
    float (*Ow)[16][64]    = reinterpret_cast<float(*)[16][64]>(smraw);

    const int flag = sniff_bf16(xs);
    const int t  = threadIdx.x;
    const int l  = t & 63;
    const int w  = t >> 6;
    const int li = l & 15;
    const int g  = l >> 4;
    const int g4 = g * 4;

    const int bid = blockIdx.x;
    const int b   = bid & 3;
    const int u   = bid >> 2;
    int qt16, c;
    if (u < 256) { qt16 = 255 - (u >> 1); c = u & 1; }
    else         { qt16 = 383 - u;        c = 0;     }
    const int q0    = qt16 * 16;
    const int nkt   = (qt16 >> 2) + 1;
    const int ktBeg = c * 32;
    const int ktEnd = min(ktBeg + 32, nkt);
    const int nc    = (qt16 >= 128) ? 2 : 1;

    const u16* qrow = qw + ((long)(b * SEQ + q0 + li)) * HD + g * 8;
    short8 qf0 = *reinterpret_cast<const short8*>(qrow);
    short8 qf1 = *reinterpret_cast<const short8*>(qrow + 32);

    short8 ones;
#pragma unroll
    for (int i = 0; i < 8; ++i) ones[i] = (short)0x3F80;  // bf16 1.0

    f32x4 O[4];
#pragma unroll
    for (int i = 0; i < 4; ++i) O[i] = (f32x4){0.f, 0.f, 0.f, 0.f};
    f32x4 l4 = (f32x4){0.f, 0.f, 0.f, 0.f};
    const int qg = q0 + li;
    const f32x4 z4 = (f32x4){0.f, 0.f, 0.f, 0.f};

    const u16* kbase = kw  + ((long)(b * SEQ) + li) * HD + g * 8;
    const u16* vbase = vTw + ((long)(b * 64)  + li) * VSTRIDE + g * 8;

    const int kt0 = ktBeg + w;
    const int ntile = (kt0 < ktEnd) ? (((ktEnd - kt0) + 3) >> 2) : 0;
    const int toffLast = (ntile - 1) * 4;

    short8 ka[8];
    auto kload = [&](int toff) {                  // clamped prefetch
        const int tt = (toff > toffLast) ? toffLast : toff;
        const u16* kp = kbase + (long)((kt0 + tt) * 64) * HD;
#pragma unroll
        for (int sub = 0; sub < 4; ++sub) {
            ka[2*sub]   = *reinterpret_cast<const short8*>(kp + sub * 16 * HD);
            ka[2*sub+1] = *reinterpret_cast<const short8*>(kp + sub * 16 * HD + 32);
        }
    };
    auto sphase = [&](int toff, int pb) {         // S^T + softmax -> Ps[w][pb]
        const int k0 = (kt0 + toff) * 64;
        const u32 mb0 = maskbits[b * 128 + (k0 >> 5)];
        const u32 mb1 = maskbits[b * 128 + (k0 >> 5) + 1];
#pragma unroll
        for (int sub = 0; sub < 4; ++sub) {
            f32x4 a = __builtin_amdgcn_mfma_f32_16x16x32_bf16(ka[2*sub],   qf0, z4, 0, 0, 0);
            a       = __builtin_amdgcn_mfma_f32_16x16x32_bf16(ka[2*sub+1], qf1, a,  0, 0, 0);
            const u32 word = (sub & 2) ? mb1 : mb0;
            float p[4];
#pragma unroll
            for (int r = 0; r < 4; ++r) {
                const int kloc = sub * 16 + g4 + r;
                const bool keep = ((k0 + kloc) <= qg) &&
                                  (((word >> ((sub & 1) * 16 + g4 + r)) & 1u) != 0u);
                p[r] = ex2(fmaf(a[r], SSCALE, keep ? CSHIFT : NEGBIG));
            }
            uint2 pk = make_uint2(pkbf(p[0], p[1]), pkbf(p[2], p[3]));
            *reinterpret_cast<uint2*>(&Ps[w][pb][li][sub * 16 + g4]) = pk;
        }
    };

    if (ntile > 0) {
        kload(0);
        sphase(0, 0);
        kload(4);
    }
    for (int i = 0; i < ntile; ++i) {
        const int k0 = (kt0 + 4 * i) * 64;
        short8 vf[8];
#pragma unroll
        for (int ds = 0; ds < 4; ++ds) {
            const u16* vr = vbase + (long)(ds * 16) * VSTRIDE + k0;
            vf[2*ds]   = *reinterpret_cast<const short8*>(vr);
            vf[2*ds+1] = *reinterpret_cast<const short8*>(vr + 32);
        }
        const int bufA = i & 1;
        short8 A1 = *reinterpret_cast<const short8*>(&Ps[w][bufA][li][g * 8]);
        short8 A2 = *reinterpret_cast<const short8*>(&Ps[w][bufA][li][32 + g * 8]);
        if (i + 1 < ntile) {
            sphase(4 * (i + 1), bufA ^ 1);        // overlaps PV(i) below
            kload(4 * (i + 2));
        }
        f32x4 lt = __builtin_amdgcn_mfma_f32_16x16x32_bf16(A1, ones, z4, 0, 0, 0);
        lt       = __builtin_amdgcn_mfma_f32_16x16x32_bf16(A2, ones, lt, 0, 0, 0);
#pragma unroll
        for (int r = 0; r < 4; ++r) l4[r] += lt[r];
#pragma unroll
        for (int ds = 0; ds < 4; ++ds) {
            O[ds] = __builtin_amdgcn_mfma_f32_16x16x32_bf16(A1, vf[2*ds],   O[ds], 0, 0, 0);
            O[ds] = __builtin_amdgcn_mfma_f32_16x16x32_bf16(A2, vf[2*ds+1], O[ds], 0, 0, 0);
        }
    }

    __syncthreads();   // all Ps reads done before Ow overlay writes
#pragma unroll
    for (int ds = 0; ds < 4; ++ds)
#pragma unroll
        for (int r = 0; r < 4; ++r)
            Ow[w][g4 + r][ds * 16 + li] = O[ds][r];
    if (li == 0) {
#pragma unroll
        for (int r = 0; r < 4; ++r) lwS[w][g4 + r] = l4[r];
    }
    __syncthreads();

    // combine 4 wave partials (plain sums); thread -> (q = t>>4, d4 = (t&15)*4)
    {
        const int qq = t >> 4;
        const int dd = (t & 15) * 4;
        float L = lwS[0][qq] + lwS[1][qq] + lwS[2][qq] + lwS[3][qq];
        float4 o0 = *reinterpret_cast<const float4*>(&Ow[0][qq][dd]);
        float4 o1 = *reinterpret_cast<const float4*>(&Ow[1][qq][dd]);
        float4 o2 = *reinterpret_cast<const float4*>(&Ow[2][qq][dd]);
        float4 o3 = *reinterpret_cast<const float4*>(&Ow[3][qq][dd]);
        float rx = o0.x + o1.x + o2.x + o3.x;
        float ry = o0.y + o1.y + o2.y + o3.y;
        float rz = o0.z + o1.z + o2.z + o3.z;
        float rw = o0.w + o1.w + o2.w + o3.w;
        if (nc == 1) {
            const float rl = (L > 0.f) ? 1.f / L : 0.f;
            rx *= rl; ry *= rl; rz *= rl; rw *= rl;
            const long row = (long)(b * SEQ + q0 + qq);
            if (flag) {
                uint2 st = make_uint2(pkbf(rx, ry), pkbf(rz, rw));
                *reinterpret_cast<uint2*>((u16*)out + row * HD + dd) = st;
            } else {
                *reinterpret_cast<float4*>((float*)out + row * HD + dd) =
                    make_float4(rx, ry, rz, rw);
            }
        } else {
            char* slot = part + ((long)((b * 128 + (qt16 - 128)) * 2 + c)) * PSLOTB;
            uint2 st = make_uint2(pkbf(rx, ry), pkbf(rz, rw));
            *reinterpret_cast<uint2*>((u16*)slot + qq * 64 + dd) = st;
            if ((t & 15) == 0)
                *reinterpret_cast<float*>(slot + 2048 + qq * 4) = L;
        }
    }
}

// ---------------- merge split-K partials (qt16 >= 128): plain sum ----------
__global__ __launch_bounds__(256) void merge_kernel(
    const u32* __restrict__ xs, const char* __restrict__ part,
    void* __restrict__ out)
{
    const int flag = sniff_bf16(xs);
    const int bid = blockIdx.x;         // 512
    const int b    = bid & 3;
    const int qt16 = 128 + (bid >> 2);
    const int t  = threadIdx.x;
    const int qq = t >> 4;
    const int dd = (t & 15) * 4;
    const char* s0 = part + ((long)((b * 128 + (qt16 - 128)) * 2)) * PSLOTB;
    const char* s1 = s0 + PSLOTB;
    float l0 = *reinterpret_cast<const float*>(s0 + 2048 + qq * 4);
    float l1 = *reinterpret_cast<const float*>(s1 + 2048 + qq * 4);
    float L  = l0 + l1;
    float rl = (L > 0.f) ? 1.f / L : 0.f;
    ushort4 a0 = *reinterpret_cast<const ushort4*>((const u16*)s0 + qq * 64 + dd);
    ushort4 a1 = *reinterpret_cast<const ushort4*>((const u16*)s1 + qq * 64 + dd);
    float rx = (bfbits2f(a0.x) + bfbits2f(a1.x)) * rl;
    float ry = (bfbits2f(a0.y) + bfbits2f(a1.y)) * rl;
    float rz = (bfbits2f(a0.z) + bfbits2f(a1.z)) * rl;
    float rw = (bfbits2f(a0.w) + bfbits2f(a1.w)) * rl;
    const long row = (long)(b * SEQ + qt16 * 16 + qq);
    if (flag) {
        uint2 st = make_uint2(pkbf(rx, ry), pkbf(rz, rw));
        *reinterpret_cast<uint2*>((u16*)out + row * HD + dd) = st;
    } else {
        *reinterpret_cast<float4*>((float*)out + row * HD + dd) =
            make_float4(rx, ry, rz, rw);
    }
}

extern "C" void kernel_launch(void* const* d_in, const int* in_sizes, int n_in,
                              void* d_out, int out_size, void* d_ws, size_t ws_size,
                              hipStream_t stream) {
    const void* x   = d_in[0];
    const int* mask = (const int*)d_in[1];
    const void* wq  = d_in[2];
    const void* wk  = d_in[3];
    const void* wv  = d_in[4];
    const u32* xs   = (const u32*)x;

    u16* q    = (u16*)d_ws;                          // 2 MB
    u16* k    = q  + (long)NROW * HD;                // 2 MB
    u16* vT   = k  + (long)NROW * HD;                // 2.16 MB
    u32* mb   = (u32*)(vT + (long)BATCH * 64 * VSTRIDE);  // 2 KB
    char* part = (char*)(mb + 512);                  // 2.13 MB

    qkv_kernel  <<<258, 512, 0, stream>>>(x, wq, wk, wv, mask, q, k, vT, mb);
    attn_kernel <<<4 * 384, 256, 0, stream>>>(xs, q, k, vT, mb, part, d_out);
    merge_kernel<<<512, 256, 0, stream>>>(xs, part, d_out);
}